// Round 4
// baseline (624.366 us; speedup 1.0000x reference)
//
#include <hip/hip_runtime.h>
#include <hip/hip_bf16.h>

#define DECAY_F 0.8f
#define OMD_F   0.2f
#define EPS_F   1e-5f

#define NROWS 16384
#define CBOOK 8192
#define DIM   256
#define KSPLIT 768   // [hi | lo | hi] x [hi | hi | lo]

// ---- ws layout (bytes) ----
#define WS_KEYS   0u            // 16384 * 8
#define WS_ENORM  131072u       // 8192 * 4
#define WS_COUNTS 163840u       // 8192 * 4
#define WS_TOTAL  196608u       // 4
#define WS_XSPLIT 262144u       // 16384*768*2 = 25165824
#define WS_ESPLIT_OFF (262144u + 25165824u)          // 25427968
#define WS_NEED   (WS_ESPLIT_OFF + 12582912u)        // 38010880

// ---- d_out layout (floats) ----
#define O_QUANT 0
#define O_IND   4194304
#define O_NORM  4210688
#define O_CSN   6307840
#define O_AVG   6316032

typedef __attribute__((ext_vector_type(8))) short short8;
typedef __attribute__((ext_vector_type(4))) float f32x4;
typedef __attribute__((ext_vector_type(4))) unsigned short us4;

__device__ __forceinline__ unsigned int fkey(float f) {
    unsigned int b = __float_as_uint(f);
    return (b & 0x80000000u) ? ~b : (b | 0x80000000u);
}
__device__ __forceinline__ unsigned short f2bf(float f) {
    unsigned int u = __float_as_uint(f);
    unsigned int r = (u + 0x7FFFu + ((u >> 16) & 1u)) >> 16;
    return (unsigned short)r;
}
__device__ __forceinline__ float bf2f(unsigned short h) {
    return __uint_as_float(((unsigned int)h) << 16);
}

#define GLOAD_LDS16(g, l) \
    __builtin_amdgcn_global_load_lds((const __attribute__((address_space(1))) void*)(g), \
                                     (__attribute__((address_space(3))) void*)(l), 16, 0, 0)

// ---------- init embed_avg_new = 0.8*embed_avg ----------
__global__ __launch_bounds__(256) void init_avg_kernel(const float* __restrict__ embed_avg,
                                                       float* __restrict__ avg_out) {
    int i = blockIdx.x * 256 + threadIdx.x;
    float4 v = ((const float4*)embed_avg)[i];
    v.x *= DECAY_F; v.y *= DECAY_F; v.z *= DECAY_F; v.w *= DECAY_F;
    ((float4*)avg_out)[i] = v;
}

// ---------- x split: [hi, lo, hi], elementwise ----------
__global__ __launch_bounds__(256) void xsplit_kernel(const float* __restrict__ src,
                                                     unsigned short* __restrict__ dst) {
    int i = blockIdx.x * 256 + threadIdx.x;      // float4 index
    int e4  = i * 4;
    int row = e4 >> 8;
    int k   = e4 & 255;
    float4 v = ((const float4*)src)[i];
    us4 hi, lo;
    hi.x = f2bf(v.x); lo.x = f2bf(v.x - bf2f(hi.x));
    hi.y = f2bf(v.y); lo.y = f2bf(v.y - bf2f(hi.y));
    hi.z = f2bf(v.z); lo.z = f2bf(v.z - bf2f(hi.z));
    hi.w = f2bf(v.w); lo.w = f2bf(v.w - bf2f(hi.w));
    unsigned short* base = dst + (size_t)row * KSPLIT + k;
    *(us4*)(base + 0)   = hi;
    *(us4*)(base + 256) = lo;
    *(us4*)(base + 512) = hi;
}

// ---------- e split [hi, hi, lo] + fused ||e||^2 (one wave per row) ----------
__global__ __launch_bounds__(256) void esplit_kernel(const float* __restrict__ embed,
                                                     unsigned short* __restrict__ dst,
                                                     float* __restrict__ enorm) {
    int row  = (blockIdx.x * 256 + threadIdx.x) >> 6;
    int lane = threadIdx.x & 63;
    float4 v = *(const float4*)&embed[row * DIM + lane * 4];
    float s = v.x * v.x + v.y * v.y + v.z * v.z + v.w * v.w;
    for (int m = 32; m >= 1; m >>= 1) s += __shfl_xor(s, m, 64);
    if (lane == 0) enorm[row] = s;
    us4 hi, lo;
    hi.x = f2bf(v.x); lo.x = f2bf(v.x - bf2f(hi.x));
    hi.y = f2bf(v.y); lo.y = f2bf(v.y - bf2f(hi.y));
    hi.z = f2bf(v.z); lo.z = f2bf(v.z - bf2f(hi.z));
    hi.w = f2bf(v.w); lo.w = f2bf(v.w - bf2f(hi.w));
    unsigned short* base = dst + (size_t)row * KSPLIT + lane * 4;
    *(us4*)(base + 0)   = hi;
    *(us4*)(base + 256) = hi;
    *(us4*)(base + 512) = lo;
}

// ============ 8-phase 256^2 MFMA GEMM (K=768) + fused per-row argmin ============
// 8 waves (wr in 0..1 -> 128 rows, wc in 0..3 -> 64 cols). BK=64.
// LDS: [buf][half][128 rows][64 k] per operand; phys_chunk = chunk ^ (row&7).
// Per K-tile: 4 phases of {12 ds_read ; stage ; s_barrier ; lgkm ; 16 MFMA ; s_barrier}.
// vmcnt wait only at phase 3 (once per K-tile). Raw asm barriers: no implicit drain.
__global__ __launch_bounds__(512, 1) void mfma8_argmin_kernel(const unsigned short* __restrict__ A,
                                                              const unsigned short* __restrict__ B,
                                                              const float* __restrict__ enorm,
                                                              unsigned long long* __restrict__ keys) {
    __shared__ __align__(16) unsigned short Al[2][2][128 * 64];   // 64 KiB
    __shared__ __align__(16) unsigned short Bl[2][2][128 * 64];   // 64 KiB

    const int tid  = threadIdx.x;
    const int lane = tid & 63;
    const int wid  = tid >> 6;      // 0..7
    const int wr   = wid >> 2;      // 0..1  (A-half = wr)
    const int wc   = wid & 3;       // 0..3  (B-half = wc>>1, sub = wc&1)
    const int lr   = lane & 15;
    const int hk   = lane >> 4;     // 0..3

    // XCD-aware bijective swizzle (2048 % 8 == 0)
    const int bid = blockIdx.x;
    const int sw  = ((bid & 7) << 8) | (bid >> 3);
    const int bx  = sw & 31;        // 32 n-blocks
    const int by  = sw >> 5;        // 64 m-blocks
    const int mBase = by * 256;
    const int nBase = bx * 256;

    f32x4 acc[8][4];
#pragma unroll
    for (int i = 0; i < 8; i++)
#pragma unroll
        for (int n = 0; n < 4; n++) acc[i][n] = (f32x4)0.f;

    // ---- staging addressing: thread tid covers phys (row = tid>>3 (+64q,+128h),
    // chunk = tid&7); logical k-chunk = (tid&7) ^ (row&7) pre-applied on source.
    const int srow = tid >> 3;                          // 0..63
    const int sck  = (((tid & 7) ^ (srow & 7)) << 3);   // element offset in 64-k tile
    const unsigned short* gA = A + (size_t)(mBase + srow) * KSPLIT + sck;
    const unsigned short* gB = B + (size_t)(nBase + srow) * KSPLIT + sck;
    const size_t rstep = (size_t)64 * KSPLIT;           // +64 rows

#define STAGE_OP(gp, lbase, t) do { \
    GLOAD_LDS16((gp) + (size_t)(t) * 64,             (lbase) + tid * 8); \
    GLOAD_LDS16((gp) + (size_t)(t) * 64 + rstep,     (lbase) + tid * 8 + 4096); \
    GLOAD_LDS16((gp) + (size_t)(t) * 64 + 2 * rstep, (lbase) + tid * 8 + 8192); \
    GLOAD_LDS16((gp) + (size_t)(t) * 64 + 3 * rstep, (lbase) + tid * 8 + 12288); \
} while (0)

    // ---- read addressing: frag (row f*16+lr), logical chunk c=s*4+hk ->
    // phys chunk c ^ (lr&7) (row&7 == lr&7 for all our rows).
    const int coff0 = ((hk    ) ^ (lr & 7)) << 3;   // s=0, elements
    const int coff1 = ((4 + hk) ^ (lr & 7)) << 3;   // s=1

    // prologue: stage K-tile 0 into buf 0
    STAGE_OP(gA, &Al[0][0][0], 0);
    STAGE_OP(gB, &Bl[0][0][0], 0);
    asm volatile("s_waitcnt vmcnt(0)" ::: "memory");
    asm volatile("s_barrier" ::: "memory");

    for (int t = 0; t < 12; ++t) {
        const int buf = t & 1;
        const unsigned short* ab = &Al[buf][wr][0];
        const unsigned short* bb = &Bl[buf][wc >> 1][(wc & 1) * 4096];
        const bool more = (t < 11);
#pragma unroll
        for (int p = 0; p < 4; ++p) {
            const int mb = (p >> 1) * 4;   // m-frag base (0 or 4)
            const int nb = (p & 1) * 2;    // n-frag base (0 or 2)

            short8 af[4][2], bf2[2][2];
#pragma unroll
            for (int i = 0; i < 4; i++) {
                const int ro = ((mb + i) * 16 + lr) * 64;
                af[i][0] = *(const short8*)&ab[ro + coff0];
                af[i][1] = *(const short8*)&ab[ro + coff1];
            }
#pragma unroll
            for (int n = 0; n < 2; n++) {
                const int ro = ((nb + n) * 16 + lr) * 64;
                bf2[n][0] = *(const short8*)&bb[ro + coff0];
                bf2[n][1] = *(const short8*)&bb[ro + coff1];
            }

            if (p == 0 && more) STAGE_OP(gA, &Al[buf ^ 1][0][0], t + 1);
            if (p == 1 && more) STAGE_OP(gB, &Bl[buf ^ 1][0][0], t + 1);
            if (p == 3 && more) asm volatile("s_waitcnt vmcnt(0)" ::: "memory");

            asm volatile("s_barrier" ::: "memory");
            asm volatile("s_waitcnt lgkmcnt(0)" ::: "memory");
            __builtin_amdgcn_sched_barrier(0);
            __builtin_amdgcn_s_setprio(1);
#pragma unroll
            for (int i = 0; i < 4; i++)
#pragma unroll
                for (int n = 0; n < 2; n++) {
                    acc[mb + i][nb + n] = __builtin_amdgcn_mfma_f32_16x16x32_bf16(
                        af[i][0], bf2[n][0], acc[mb + i][nb + n], 0, 0, 0);
                    acc[mb + i][nb + n] = __builtin_amdgcn_mfma_f32_16x16x32_bf16(
                        af[i][1], bf2[n][1], acc[mb + i][nb + n], 0, 0, 0);
                }
            __builtin_amdgcn_s_setprio(0);
            asm volatile("s_barrier" ::: "memory");
        }
    }
#undef STAGE_OP

    // epilogue: score = ||e||^2 - 2*dot; per-row argmin; deterministic key-min
    float en4[4];
    int   c4[4];
#pragma unroll
    for (int n = 0; n < 4; n++) {
        c4[n]  = nBase + wc * 64 + n * 16 + lr;
        en4[n] = enorm[c4[n]];
    }
#pragma unroll
    for (int i = 0; i < 8; i++) {
#pragma unroll
        for (int reg = 0; reg < 4; reg++) {
            float bs = 3.4e38f; int bc = 0;
#pragma unroll
            for (int n = 0; n < 4; n++) {
                float s = en4[n] - 2.f * acc[i][n][reg];
                if (s < bs || (s == bs && c4[n] < bc)) { bs = s; bc = c4[n]; }
            }
            unsigned long long key =
                ((unsigned long long)fkey(bs) << 32) | (unsigned int)bc;
#pragma unroll
            for (int m = 8; m >= 1; m >>= 1) {
                unsigned long long o = __shfl_xor(key, m, 64);
                if (o < key) key = o;
            }
            if (lr == 0)
                atomicMin(&keys[mBase + wr * 128 + i * 16 + hk * 4 + reg], key);
        }
    }
}

// ---------- fallback fp32 fused GEMM+argmin ----------
#define BM 64
#define BN 256
#define KB 16
#define NSPLIT 4

__global__ __launch_bounds__(256) void argmin_kernel(const float* __restrict__ x,
                                                     const float* __restrict__ embed,
                                                     const float* __restrict__ enorm,
                                                     unsigned long long* __restrict__ keys) {
    __shared__ float xs[KB][BM];
    __shared__ float es[KB][BN];

    const int tid = threadIdx.x;
    const int tx = tid & 31;
    const int ty = tid >> 5;
    const int rowBase = blockIdx.x * BM;
    const int cStart = blockIdx.y * (CBOOK / NSPLIT);

    float bestS[8];
    int   bestC[8];
#pragma unroll
    for (int i = 0; i < 8; i++) { bestS[i] = 3.4e38f; bestC[i] = 0; }

    float acc[8][8];

    for (int cb = 0; cb < CBOOK / NSPLIT; cb += BN) {
        const int cbase = cStart + cb;
#pragma unroll
        for (int i = 0; i < 8; i++)
#pragma unroll
            for (int j = 0; j < 8; j++) acc[i][j] = 0.f;

        for (int kk = 0; kk < DIM; kk += KB) {
            __syncthreads();
            {
                int r  = tid >> 2;
                int k4 = (tid & 3) * 4;
                float4 v = *(const float4*)&x[(rowBase + r) * DIM + kk + k4];
                xs[k4 + 0][r] = v.x; xs[k4 + 1][r] = v.y;
                xs[k4 + 2][r] = v.z; xs[k4 + 3][r] = v.w;
            }
            {
                const float4* src = (const float4*)&embed[(cbase + tid) * DIM + kk];
#pragma unroll
                for (int q = 0; q < 4; q++) {
                    float4 v = src[q];
                    es[q * 4 + 0][tid] = v.x; es[q * 4 + 1][tid] = v.y;
                    es[q * 4 + 2][tid] = v.z; es[q * 4 + 3][tid] = v.w;
                }
            }
            __syncthreads();
#pragma unroll
            for (int k = 0; k < KB; k++) {
                float xr[8], er[8];
                *(float4*)&xr[0] = *(const float4*)&xs[k][ty * 8];
                *(float4*)&xr[4] = *(const float4*)&xs[k][ty * 8 + 4];
                *(float4*)&er[0] = *(const float4*)&es[k][tx * 4];
                *(float4*)&er[4] = *(const float4*)&es[k][128 + tx * 4];
#pragma unroll
                for (int i = 0; i < 8; i++)
#pragma unroll
                    for (int j = 0; j < 8; j++)
                        acc[i][j] = fmaf(xr[i], er[j], acc[i][j]);
            }
        }
#pragma unroll
        for (int j = 0; j < 8; j++) {
            int c = cbase + ((j < 4) ? (tx * 4 + j) : (128 + tx * 4 + (j - 4)));
            float en = enorm[c];
#pragma unroll
            for (int i = 0; i < 8; i++) {
                float s = en - 2.f * acc[i][j];
                if (s < bestS[i]) { bestS[i] = s; bestC[i] = c; }
            }
        }
    }

#pragma unroll
    for (int i = 0; i < 8; i++) {
        unsigned long long key =
            ((unsigned long long)fkey(bestS[i]) << 32) | (unsigned int)bestC[i];
        for (int m = 16; m >= 1; m >>= 1) {
            unsigned long long o = __shfl_xor(key, m, 64);
            if (o < key) key = o;
        }
        if (tx == 0) atomicMin(&keys[rowBase + ty * 8 + i], key);
    }
}

// ---------- scatter: quantize gather, ind write, counts, 0.2*x into avg ----------
__global__ __launch_bounds__(256) void scatter_kernel(const float* __restrict__ x,
                                                      const float* __restrict__ embed,
                                                      const unsigned long long* __restrict__ keys,
                                                      float* __restrict__ quant,
                                                      float* __restrict__ ind_out,
                                                      float* __restrict__ counts,
                                                      float* __restrict__ avg_out) {
    int i = blockIdx.x * 256 + threadIdx.x;
    int row = i >> 6;
    int c4  = (i & 63) * 4;
    int idx = (int)(keys[row] & 0xFFFFFFFFull);
    float4 e = *(const float4*)&embed[idx * DIM + c4];
    *(float4*)&quant[row * DIM + c4] = e;
    float4 xv = *(const float4*)&x[row * DIM + c4];
    atomicAdd(&avg_out[idx * DIM + c4 + 0], OMD_F * xv.x);
    atomicAdd(&avg_out[idx * DIM + c4 + 1], OMD_F * xv.y);
    atomicAdd(&avg_out[idx * DIM + c4 + 2], OMD_F * xv.z);
    atomicAdd(&avg_out[idx * DIM + c4 + 3], OMD_F * xv.w);
    if ((i & 63) == 0) {
        ind_out[row] = (float)idx;
        atomicAdd(&counts[idx], 1.0f);
    }
}

// ---------- cluster_size_new + total sum ----------
__global__ __launch_bounds__(256) void csn_kernel(const float* __restrict__ cluster_size,
                                                  const float* __restrict__ counts,
                                                  float* __restrict__ csn_out,
                                                  float* __restrict__ total) {
    int c = blockIdx.x * 256 + threadIdx.x;
    float v = DECAY_F * cluster_size[c] + OMD_F * counts[c];
    csn_out[c] = v;
    float s = v;
    for (int m = 32; m >= 1; m >>= 1) s += __shfl_xor(s, m, 64);
    __shared__ float ws4[4];
    if ((threadIdx.x & 63) == 0) ws4[threadIdx.x >> 6] = s;
    __syncthreads();
    if (threadIdx.x == 0) atomicAdd(total, ws4[0] + ws4[1] + ws4[2] + ws4[3]);
}

// ---------- embed_normalized = avg_new / cs ----------
__global__ __launch_bounds__(256) void norm_kernel(const float* __restrict__ avg_new,
                                                   const float* __restrict__ csn,
                                                   const float* __restrict__ total,
                                                   float* __restrict__ out) {
    int i = blockIdx.x * 256 + threadIdx.x;
    int c = i >> 6;
    float tot = *total;
    float smoothed = (csn[c] + EPS_F) / (tot + (float)CBOOK * EPS_F);
    float cs = smoothed * tot;
    float4 v = ((const float4*)avg_new)[i];
    v.x = v.x / cs; v.y = v.y / cs; v.z = v.z / cs; v.w = v.w / cs;
    ((float4*)out)[i] = v;
}

extern "C" void kernel_launch(void* const* d_in, const int* in_sizes, int n_in,
                              void* d_out, int out_size, void* d_ws, size_t ws_size,
                              hipStream_t stream) {
    const float* x            = (const float*)d_in[0];
    const float* embed        = (const float*)d_in[1];
    const float* cluster_size = (const float*)d_in[2];
    const float* embed_avg    = (const float*)d_in[3];
    float* out = (float*)d_out;
    char*  ws  = (char*)d_ws;

    unsigned long long* keys = (unsigned long long*)(ws + WS_KEYS);
    float* enorm  = (float*)(ws + WS_ENORM);
    float* counts = (float*)(ws + WS_COUNTS);
    float* total  = (float*)(ws + WS_TOTAL);

    hipMemsetAsync(ws + WS_KEYS, 0xFF, NROWS * 8, stream);
    hipMemsetAsync(ws + WS_COUNTS, 0, CBOOK * 4 + 4, stream);

    init_avg_kernel<<<(CBOOK * DIM / 4) / 256, 256, 0, stream>>>(embed_avg, out + O_AVG);

    if (ws_size >= (size_t)WS_NEED) {
        unsigned short* xsplit = (unsigned short*)(ws + WS_XSPLIT);
        unsigned short* esplit = (unsigned short*)(ws + WS_ESPLIT_OFF);
        xsplit_kernel<<<(NROWS * DIM / 4) / 256, 256, 0, stream>>>(x, xsplit);
        esplit_kernel<<<CBOOK / 4, 256, 0, stream>>>(embed, esplit, enorm);
        mfma8_argmin_kernel<<<(NROWS / 256) * (CBOOK / 256), 512, 0, stream>>>(
            xsplit, esplit, enorm, keys);
    } else {
        esplit_kernel<<<CBOOK / 4, 256, 0, stream>>>(embed, (unsigned short*)(ws + WS_XSPLIT), enorm);
        dim3 grid(NROWS / BM, NSPLIT);
        argmin_kernel<<<grid, 256, 0, stream>>>(x, embed, enorm, keys);
    }

    scatter_kernel<<<(NROWS * DIM / 4) / 256, 256, 0, stream>>>(
        x, embed, keys, out + O_QUANT, out + O_IND, counts, out + O_AVG);

    csn_kernel<<<CBOOK / 256, 256, 0, stream>>>(cluster_size, counts, out + O_CSN, total);

    norm_kernel<<<(CBOOK * DIM / 4) / 256, 256, 0, stream>>>(
        out + O_AVG, out + O_CSN, total, out + O_NORM);
}

// Round 5
// 512.153 us; speedup vs baseline: 1.2191x; 1.2191x over previous
//
#include <hip/hip_runtime.h>
#include <hip/hip_bf16.h>

#define DECAY_F 0.8f
#define OMD_F   0.2f
#define EPS_F   1e-5f

#define NROWS 16384
#define CBOOK 8192
#define DIM   256
#define KSPLIT 768   // [hi | lo | hi] x [hi | hi | lo]

// ---- ws layout (bytes) ----
#define WS_KEYS   0u
#define WS_ENORM  131072u
#define WS_COUNTS 163840u
#define WS_TOTAL  196608u
#define WS_XSPLIT 262144u
#define WS_ESPLIT_OFF (262144u + 25165824u)
#define WS_NEED   (WS_ESPLIT_OFF + 12582912u)

// ---- d_out layout (floats) ----
#define O_QUANT 0
#define O_IND   4194304
#define O_NORM  4210688
#define O_CSN   6307840
#define O_AVG   6316032

typedef __attribute__((ext_vector_type(8)))  short short8;
typedef __attribute__((ext_vector_type(4)))  float f32x4;
typedef __attribute__((ext_vector_type(16))) float f32x16;
typedef __attribute__((ext_vector_type(4)))  unsigned short us4;

__device__ __forceinline__ unsigned int fkey(float f) {
    unsigned int b = __float_as_uint(f);
    return (b & 0x80000000u) ? ~b : (b | 0x80000000u);
}
__device__ __forceinline__ unsigned short f2bf(float f) {
    unsigned int u = __float_as_uint(f);
    unsigned int r = (u + 0x7FFFu + ((u >> 16) & 1u)) >> 16;
    return (unsigned short)r;
}
__device__ __forceinline__ float bf2f(unsigned short h) {
    return __uint_as_float(((unsigned int)h) << 16);
}

#define GLOAD_LDS16(g, l) \
    __builtin_amdgcn_global_load_lds((const __attribute__((address_space(1))) void*)(g), \
                                     (__attribute__((address_space(3))) void*)(l), 16, 0, 0)

// ---------- init embed_avg_new = 0.8*embed_avg ----------
__global__ __launch_bounds__(256) void init_avg_kernel(const float* __restrict__ embed_avg,
                                                       float* __restrict__ avg_out) {
    int i = blockIdx.x * 256 + threadIdx.x;
    float4 v = ((const float4*)embed_avg)[i];
    v.x *= DECAY_F; v.y *= DECAY_F; v.z *= DECAY_F; v.w *= DECAY_F;
    ((float4*)avg_out)[i] = v;
}

// ---------- x split: [hi, lo, hi] ----------
__global__ __launch_bounds__(256) void xsplit_kernel(const float* __restrict__ src,
                                                     unsigned short* __restrict__ dst) {
    int i = blockIdx.x * 256 + threadIdx.x;
    int e4  = i * 4;
    int row = e4 >> 8;
    int k   = e4 & 255;
    float4 v = ((const float4*)src)[i];
    us4 hi, lo;
    hi.x = f2bf(v.x); lo.x = f2bf(v.x - bf2f(hi.x));
    hi.y = f2bf(v.y); lo.y = f2bf(v.y - bf2f(hi.y));
    hi.z = f2bf(v.z); lo.z = f2bf(v.z - bf2f(hi.z));
    hi.w = f2bf(v.w); lo.w = f2bf(v.w - bf2f(hi.w));
    unsigned short* base = dst + (size_t)row * KSPLIT + k;
    *(us4*)(base + 0)   = hi;
    *(us4*)(base + 256) = lo;
    *(us4*)(base + 512) = hi;
}

// ---------- e split [hi, hi, lo] + fused ||e||^2 ----------
__global__ __launch_bounds__(256) void esplit_kernel(const float* __restrict__ embed,
                                                     unsigned short* __restrict__ dst,
                                                     float* __restrict__ enorm) {
    int row  = (blockIdx.x * 256 + threadIdx.x) >> 6;
    int lane = threadIdx.x & 63;
    float4 v = *(const float4*)&embed[row * DIM + lane * 4];
    float s = v.x * v.x + v.y * v.y + v.z * v.z + v.w * v.w;
    for (int m = 32; m >= 1; m >>= 1) s += __shfl_xor(s, m, 64);
    if (lane == 0) enorm[row] = s;
    us4 hi, lo;
    hi.x = f2bf(v.x); lo.x = f2bf(v.x - bf2f(hi.x));
    hi.y = f2bf(v.y); lo.y = f2bf(v.y - bf2f(hi.y));
    hi.z = f2bf(v.z); lo.z = f2bf(v.z - bf2f(hi.z));
    hi.w = f2bf(v.w); lo.w = f2bf(v.w - bf2f(hi.w));
    unsigned short* base = dst + (size_t)row * KSPLIT + lane * 4;
    *(us4*)(base + 0)   = hi;
    *(us4*)(base + 256) = hi;
    *(us4*)(base + 512) = lo;
}

// ============ 32x32x16 MFMA GEMM (K=768) + fused per-row argmin ============
// Block 256x128, 4 waves (2x2), wave = 128x64 (M_rep4 x N_rep2 of 32x32 frags).
// BK=32, 3 LDS buffers, depth-2 prefetch, counted vmcnt(6), ONE s_barrier/tile.
// LDS rows = 32 elems (64B); 4-spread XOR chunk swizzle (R3-proven, 0 conflicts).
__global__ __launch_bounds__(256, 2) void mfma32_argmin_kernel(
        const unsigned short* __restrict__ A,
        const unsigned short* __restrict__ B,
        const float* __restrict__ enorm,
        unsigned long long* __restrict__ keys) {
    __shared__ __align__(16) unsigned short Al[3][8192];   // 3 x 16 KB (256r x 32k)
    __shared__ __align__(16) unsigned short Bl[3][4096];   // 3 x  8 KB (128r x 32k)

    const int tid  = threadIdx.x;
    const int lane = tid & 63;
    const int wid  = tid >> 6;
    const int wr   = wid >> 1;      // 0..1 -> 128-row half of A-tile
    const int wc   = wid & 1;       // 0..1 -> 64-col half of B-tile
    const int l31  = lane & 31;
    const int hi5  = lane >> 5;

    // grid 64x64; XCD-bijective + 8x8 super-tile chunking for L2
    const int bid  = blockIdx.x;
    const int swz  = ((bid & 7) << 9) | (bid >> 3);   // 4096 % 8 == 0
    const int stid = swz >> 6, win = swz & 63;
    const int by   = ((stid >> 3) << 3) + (win >> 3);
    const int bx   = ((stid & 7) << 3) + (win & 7);
    const int mBase = by << 8;   // * 256
    const int nBase = bx << 7;   // * 128

    f32x16 acc[4][2];
#pragma unroll
    for (int m = 0; m < 4; m++)
#pragma unroll
        for (int n = 0; n < 2; n++) acc[m][n] = (f32x16)0.f;

    // ---- staging: A 4 calls/thread, B 2 calls/thread, 16B each.
    // slot s -> (row = s>>2, physchunk = s&3); logical chunk = phys ^ (row&3)
    // (source pre-swizzle; LDS dest stays linear: rule #21).
    const unsigned short* pA[4];
    int dA[4];
#pragma unroll
    for (int c = 0; c < 4; c++) {
        int slot = (wid * 4 + c) * 64 + lane;        // 0..1023
        int row  = slot >> 2;
        int lg   = (slot & 3) ^ (row & 3);
        pA[c] = A + (size_t)(mBase + row) * KSPLIT + lg * 8;
        dA[c] = slot * 8;                            // shorts
    }
    const unsigned short* pB[2];
    int dB[2];
#pragma unroll
    for (int c = 0; c < 2; c++) {
        int slot = (wid * 2 + c) * 64 + lane;        // 0..511
        int row  = slot >> 2;
        int lg   = (slot & 3) ^ (row & 3);
        pB[c] = B + (size_t)(nBase + row) * KSPLIT + lg * 8;
        dB[c] = slot * 8;
    }

#define STAGE(bufn, t) do { \
    _Pragma("unroll") for (int c = 0; c < 4; c++) \
        GLOAD_LDS16(pA[c] + (t) * 32, &Al[bufn][dA[c]]); \
    _Pragma("unroll") for (int c = 0; c < 2; c++) \
        GLOAD_LDS16(pB[c] + (t) * 32, &Bl[bufn][dB[c]]); \
} while (0)

    // ---- read offsets: row R, chunk c(ks,hi5) -> phys = c ^ (R&3), R&3 == l31&3
    const int cx = l31 & 3;
    const int co0 = ((0 * 2 + hi5) ^ cx) * 8;   // ks=0, shorts
    const int co1 = ((1 * 2 + hi5) ^ cx) * 8;   // ks=1
    int arow[4], brow[2];
#pragma unroll
    for (int m = 0; m < 4; m++) arow[m] = (wr * 128 + m * 32 + l31) * 32;
#pragma unroll
    for (int n = 0; n < 2; n++) brow[n] = (wc * 64 + n * 32 + l31) * 32;

    STAGE(0, 0);
    STAGE(1, 1);

    int b0 = 0, b1 = 1, b2 = 2;
    for (int t = 0; t < 24; ++t) {
        if (t < 23) asm volatile("s_waitcnt vmcnt(6)" ::: "memory");
        else        asm volatile("s_waitcnt vmcnt(0)" ::: "memory");
        asm volatile("s_barrier" ::: "memory");
        if (t < 22) STAGE(b2, t + 2);

        short8 af[4][2], bf[2][2];
#pragma unroll
        for (int m = 0; m < 4; m++) {
            af[m][0] = *(const short8*)&Al[b0][arow[m] + co0];
            af[m][1] = *(const short8*)&Al[b0][arow[m] + co1];
        }
#pragma unroll
        for (int n = 0; n < 2; n++) {
            bf[n][0] = *(const short8*)&Bl[b0][brow[n] + co0];
            bf[n][1] = *(const short8*)&Bl[b0][brow[n] + co1];
        }
        asm volatile("s_waitcnt lgkmcnt(0)" ::: "memory");
        __builtin_amdgcn_sched_barrier(0);
        __builtin_amdgcn_s_setprio(1);
#pragma unroll
        for (int m = 0; m < 4; m++)
#pragma unroll
            for (int n = 0; n < 2; n++) {
                acc[m][n] = __builtin_amdgcn_mfma_f32_32x32x16_bf16(
                    af[m][0], bf[n][0], acc[m][n], 0, 0, 0);
                acc[m][n] = __builtin_amdgcn_mfma_f32_32x32x16_bf16(
                    af[m][1], bf[n][1], acc[m][n], 0, 0, 0);
            }
        __builtin_amdgcn_s_setprio(0);

        int nb0 = b1; b1 = b2; b2 = b0; b0 = nb0;   // rotate buffers
    }
#undef STAGE

    // ---- epilogue: score = ||e||^2 - 2*dot; argmin per row (32x32 C/D layout:
    // col = lane&31, row = (reg&3) + 8*(reg>>2) + 4*(lane>>5)  [m74/m101])
    float en[2];
    int   cc[2];
#pragma unroll
    for (int n = 0; n < 2; n++) {
        cc[n] = nBase + wc * 64 + n * 32 + l31;
        en[n] = enorm[cc[n]];
    }
#pragma unroll
    for (int m = 0; m < 4; m++) {
#pragma unroll
        for (int r = 0; r < 16; r++) {
            float s0 = en[0] - 2.f * acc[m][0][r];
            float s1 = en[1] - 2.f * acc[m][1][r];
            float bs = s0; int bc = cc[0];
            if (s1 < bs) { bs = s1; bc = cc[1]; }   // tie -> lower col (cc0<cc1)
            unsigned long long key =
                ((unsigned long long)fkey(bs) << 32) | (unsigned int)bc;
#pragma unroll
            for (int msk = 16; msk >= 1; msk >>= 1) {
                unsigned long long o = __shfl_xor(key, msk, 64);
                if (o < key) key = o;
            }
            if (l31 == 0) {
                int grow = mBase + wr * 128 + m * 32 + (r & 3) + 8 * (r >> 2) + 4 * hi5;
                atomicMin(&keys[grow], key);
            }
        }
    }
}

// ---------- fallback fp32 fused GEMM+argmin ----------
#define BM 64
#define BN 256
#define KB 16
#define NSPLIT 4

__global__ __launch_bounds__(256) void argmin_kernel(const float* __restrict__ x,
                                                     const float* __restrict__ embed,
                                                     const float* __restrict__ enorm,
                                                     unsigned long long* __restrict__ keys) {
    __shared__ float xs[KB][BM];
    __shared__ float es[KB][BN];

    const int tid = threadIdx.x;
    const int tx = tid & 31;
    const int ty = tid >> 5;
    const int rowBase = blockIdx.x * BM;
    const int cStart = blockIdx.y * (CBOOK / NSPLIT);

    float bestS[8];
    int   bestC[8];
#pragma unroll
    for (int i = 0; i < 8; i++) { bestS[i] = 3.4e38f; bestC[i] = 0; }

    float acc[8][8];

    for (int cb = 0; cb < CBOOK / NSPLIT; cb += BN) {
        const int cbase = cStart + cb;
#pragma unroll
        for (int i = 0; i < 8; i++)
#pragma unroll
            for (int j = 0; j < 8; j++) acc[i][j] = 0.f;

        for (int kk = 0; kk < DIM; kk += KB) {
            __syncthreads();
            {
                int r  = tid >> 2;
                int k4 = (tid & 3) * 4;
                float4 v = *(const float4*)&x[(rowBase + r) * DIM + kk + k4];
                xs[k4 + 0][r] = v.x; xs[k4 + 1][r] = v.y;
                xs[k4 + 2][r] = v.z; xs[k4 + 3][r] = v.w;
            }
            {
                const float4* src = (const float4*)&embed[(cbase + tid) * DIM + kk];
#pragma unroll
                for (int q = 0; q < 4; q++) {
                    float4 v = src[q];
                    es[q * 4 + 0][tid] = v.x; es[q * 4 + 1][tid] = v.y;
                    es[q * 4 + 2][tid] = v.z; es[q * 4 + 3][tid] = v.w;
                }
            }
            __syncthreads();
#pragma unroll
            for (int k = 0; k < KB; k++) {
                float xr[8], er[8];
                *(float4*)&xr[0] = *(const float4*)&xs[k][ty * 8];
                *(float4*)&xr[4] = *(const float4*)&xs[k][ty * 8 + 4];
                *(float4*)&er[0] = *(const float4*)&es[k][tx * 4];
                *(float4*)&er[4] = *(const float4*)&es[k][128 + tx * 4];
#pragma unroll
                for (int i = 0; i < 8; i++)
#pragma unroll
                    for (int j = 0; j < 8; j++)
                        acc[i][j] = fmaf(xr[i], er[j], acc[i][j]);
            }
        }
#pragma unroll
        for (int j = 0; j < 8; j++) {
            int c = cbase + ((j < 4) ? (tx * 4 + j) : (128 + tx * 4 + (j - 4)));
            float en = enorm[c];
#pragma unroll
            for (int i = 0; i < 8; i++) {
                float s = en - 2.f * acc[i][j];
                if (s < bestS[i]) { bestS[i] = s; bestC[i] = c; }
            }
        }
    }

#pragma unroll
    for (int i = 0; i < 8; i++) {
        unsigned long long key =
            ((unsigned long long)fkey(bestS[i]) << 32) | (unsigned int)bestC[i];
        for (int m = 16; m >= 1; m >>= 1) {
            unsigned long long o = __shfl_xor(key, m, 64);
            if (o < key) key = o;
        }
        if (tx == 0) atomicMin(&keys[rowBase + ty * 8 + i], key);
    }
}

// ---------- scatter: quantize gather, ind write, counts, 0.2*x into avg ----------
__global__ __launch_bounds__(256) void scatter_kernel(const float* __restrict__ x,
                                                      const float* __restrict__ embed,
                                                      const unsigned long long* __restrict__ keys,
                                                      float* __restrict__ quant,
                                                      float* __restrict__ ind_out,
                                                      float* __restrict__ counts,
                                                      float* __restrict__ avg_out) {
    int i = blockIdx.x * 256 + threadIdx.x;
    int row = i >> 6;
    int c4  = (i & 63) * 4;
    int idx = (int)(keys[row] & 0xFFFFFFFFull);
    float4 e = *(const float4*)&embed[idx * DIM + c4];
    *(float4*)&quant[row * DIM + c4] = e;
    float4 xv = *(const float4*)&x[row * DIM + c4];
    atomicAdd(&avg_out[idx * DIM + c4 + 0], OMD_F * xv.x);
    atomicAdd(&avg_out[idx * DIM + c4 + 1], OMD_F * xv.y);
    atomicAdd(&avg_out[idx * DIM + c4 + 2], OMD_F * xv.z);
    atomicAdd(&avg_out[idx * DIM + c4 + 3], OMD_F * xv.w);
    if ((i & 63) == 0) {
        ind_out[row] = (float)idx;
        atomicAdd(&counts[idx], 1.0f);
    }
}

// ---------- cluster_size_new + total sum ----------
__global__ __launch_bounds__(256) void csn_kernel(const float* __restrict__ cluster_size,
                                                  const float* __restrict__ counts,
                                                  float* __restrict__ csn_out,
                                                  float* __restrict__ total) {
    int c = blockIdx.x * 256 + threadIdx.x;
    float v = DECAY_F * cluster_size[c] + OMD_F * counts[c];
    csn_out[c] = v;
    float s = v;
    for (int m = 32; m >= 1; m >>= 1) s += __shfl_xor(s, m, 64);
    __shared__ float ws4[4];
    if ((threadIdx.x & 63) == 0) ws4[threadIdx.x >> 6] = s;
    __syncthreads();
    if (threadIdx.x == 0) atomicAdd(total, ws4[0] + ws4[1] + ws4[2] + ws4[3]);
}

// ---------- embed_normalized = avg_new / cs ----------
__global__ __launch_bounds__(256) void norm_kernel(const float* __restrict__ avg_new,
                                                   const float* __restrict__ csn,
                                                   const float* __restrict__ total,
                                                   float* __restrict__ out) {
    int i = blockIdx.x * 256 + threadIdx.x;
    int c = i >> 6;
    float tot = *total;
    float smoothed = (csn[c] + EPS_F) / (tot + (float)CBOOK * EPS_F);
    float cs = smoothed * tot;
    float4 v = ((const float4*)avg_new)[i];
    v.x = v.x / cs; v.y = v.y / cs; v.z = v.z / cs; v.w = v.w / cs;
    ((float4*)out)[i] = v;
}

extern "C" void kernel_launch(void* const* d_in, const int* in_sizes, int n_in,
                              void* d_out, int out_size, void* d_ws, size_t ws_size,
                              hipStream_t stream) {
    const float* x            = (const float*)d_in[0];
    const float* embed        = (const float*)d_in[1];
    const float* cluster_size = (const float*)d_in[2];
    const float* embed_avg    = (const float*)d_in[3];
    float* out = (float*)d_out;
    char*  ws  = (char*)d_ws;

    unsigned long long* keys = (unsigned long long*)(ws + WS_KEYS);
    float* enorm  = (float*)(ws + WS_ENORM);
    float* counts = (float*)(ws + WS_COUNTS);
    float* total  = (float*)(ws + WS_TOTAL);

    hipMemsetAsync(ws + WS_KEYS, 0xFF, NROWS * 8, stream);
    hipMemsetAsync(ws + WS_COUNTS, 0, CBOOK * 4 + 4, stream);

    init_avg_kernel<<<(CBOOK * DIM / 4) / 256, 256, 0, stream>>>(embed_avg, out + O_AVG);

    if (ws_size >= (size_t)WS_NEED) {
        unsigned short* xsplit = (unsigned short*)(ws + WS_XSPLIT);
        unsigned short* esplit = (unsigned short*)(ws + WS_ESPLIT_OFF);
        xsplit_kernel<<<(NROWS * DIM / 4) / 256, 256, 0, stream>>>(x, xsplit);
        esplit_kernel<<<CBOOK / 4, 256, 0, stream>>>(embed, esplit, enorm);
        mfma32_argmin_kernel<<<(NROWS / 256) * (CBOOK / 128), 256, 0, stream>>>(
            xsplit, esplit, enorm, keys);
    } else {
        esplit_kernel<<<CBOOK / 4, 256, 0, stream>>>(embed, (unsigned short*)(ws + WS_XSPLIT), enorm);
        dim3 grid(NROWS / BM, NSPLIT);
        argmin_kernel<<<grid, 256, 0, stream>>>(x, embed, enorm, keys);
    }

    scatter_kernel<<<(NROWS * DIM / 4) / 256, 256, 0, stream>>>(
        x, embed, keys, out + O_QUANT, out + O_IND, counts, out + O_AVG);

    csn_kernel<<<CBOOK / 256, 256, 0, stream>>>(cluster_size, counts, out + O_CSN, total);

    norm_kernel<<<(CBOOK * DIM / 4) / 256, 256, 0, stream>>>(
        out + O_AVG, out + O_CSN, total, out + O_NORM);
}

// Round 6
// 473.869 us; speedup vs baseline: 1.3176x; 1.0808x over previous
//
#include <hip/hip_runtime.h>
#include <hip/hip_bf16.h>

#define DECAY_F 0.8f
#define OMD_F   0.2f
#define EPS_F   1e-5f

#define NROWS 16384
#define CBOOK 8192
#define DIM   256
#define KSPLIT 768   // [hi | lo | hi] x [hi | hi | lo]

// ---- ws layout (bytes) ----
#define WS_KEYS   0u
#define WS_ENORM  131072u
#define WS_COUNTS 163840u
#define WS_TOTAL  196608u
#define WS_XSPLIT 262144u
#define WS_ESPLIT_OFF (262144u + 25165824u)
#define WS_NEED   (WS_ESPLIT_OFF + 12582912u)

// ---- d_out layout (floats) ----
#define O_QUANT 0
#define O_IND   4194304
#define O_NORM  4210688
#define O_CSN   6307840
#define O_AVG   6316032

typedef __attribute__((ext_vector_type(8)))  short short8;
typedef __attribute__((ext_vector_type(4)))  float f32x4;
typedef __attribute__((ext_vector_type(16))) float f32x16;
typedef __attribute__((ext_vector_type(4)))  unsigned short us4;

__device__ __forceinline__ unsigned int fkey(float f) {
    unsigned int b = __float_as_uint(f);
    return (b & 0x80000000u) ? ~b : (b | 0x80000000u);
}
__device__ __forceinline__ unsigned short f2bf(float f) {
    unsigned int u = __float_as_uint(f);
    unsigned int r = (u + 0x7FFFu + ((u >> 16) & 1u)) >> 16;
    return (unsigned short)r;
}
__device__ __forceinline__ float bf2f(unsigned short h) {
    return __uint_as_float(((unsigned int)h) << 16);
}

#define GLOAD_LDS16(g, l) \
    __builtin_amdgcn_global_load_lds((const __attribute__((address_space(1))) void*)(g), \
                                     (__attribute__((address_space(3))) void*)(l), 16, 0, 0)

// ---------- init embed_avg_new = 0.8*embed_avg ----------
__global__ __launch_bounds__(256) void init_avg_kernel(const float* __restrict__ embed_avg,
                                                       float* __restrict__ avg_out) {
    int i = blockIdx.x * 256 + threadIdx.x;
    float4 v = ((const float4*)embed_avg)[i];
    v.x *= DECAY_F; v.y *= DECAY_F; v.z *= DECAY_F; v.w *= DECAY_F;
    ((float4*)avg_out)[i] = v;
}

// ---------- x split: [hi, lo, hi] ----------
__global__ __launch_bounds__(256) void xsplit_kernel(const float* __restrict__ src,
                                                     unsigned short* __restrict__ dst) {
    int i = blockIdx.x * 256 + threadIdx.x;
    int e4  = i * 4;
    int row = e4 >> 8;
    int k   = e4 & 255;
    float4 v = ((const float4*)src)[i];
    us4 hi, lo;
    hi.x = f2bf(v.x); lo.x = f2bf(v.x - bf2f(hi.x));
    hi.y = f2bf(v.y); lo.y = f2bf(v.y - bf2f(hi.y));
    hi.z = f2bf(v.z); lo.z = f2bf(v.z - bf2f(hi.z));
    hi.w = f2bf(v.w); lo.w = f2bf(v.w - bf2f(hi.w));
    unsigned short* base = dst + (size_t)row * KSPLIT + k;
    *(us4*)(base + 0)   = hi;
    *(us4*)(base + 256) = lo;
    *(us4*)(base + 512) = hi;
}

// ---------- e split [hi, hi, lo] + fused ||e||^2 ----------
__global__ __launch_bounds__(256) void esplit_kernel(const float* __restrict__ embed,
                                                     unsigned short* __restrict__ dst,
                                                     float* __restrict__ enorm) {
    int row  = (blockIdx.x * 256 + threadIdx.x) >> 6;
    int lane = threadIdx.x & 63;
    float4 v = *(const float4*)&embed[row * DIM + lane * 4];
    float s = v.x * v.x + v.y * v.y + v.z * v.z + v.w * v.w;
    for (int m = 32; m >= 1; m >>= 1) s += __shfl_xor(s, m, 64);
    if (lane == 0) enorm[row] = s;
    us4 hi, lo;
    hi.x = f2bf(v.x); lo.x = f2bf(v.x - bf2f(hi.x));
    hi.y = f2bf(v.y); lo.y = f2bf(v.y - bf2f(hi.y));
    hi.z = f2bf(v.z); lo.z = f2bf(v.z - bf2f(hi.z));
    hi.w = f2bf(v.w); lo.w = f2bf(v.w - bf2f(hi.w));
    unsigned short* base = dst + (size_t)row * KSPLIT + lane * 4;
    *(us4*)(base + 0)   = hi;
    *(us4*)(base + 256) = hi;
    *(us4*)(base + 512) = lo;
}

// ============ 32x32x16 MFMA GEMM (K=768) + fused per-row argmin ============
// Block 256x128, 4 waves (2x2), wave = 128x64 (M_rep4 x N_rep2 of 32x32 frags).
// BK=32, 3 LDS buffers, depth-2 prefetch, counted vmcnt(6), ONE s_barrier/tile.
// LDS rows = 32 elems (64B). Chunk swizzle XORs with (row>>1)&3 — decorrelated
// from the row-parity bank bit (R5 bug: XOR with row&3 collapsed 8 bank groups
// to 4 -> 2x LDS cycles). Enumerated: 2 lanes/4-bank-group = free (m136).
__global__ __launch_bounds__(256, 2) void mfma32_argmin_kernel(
        const unsigned short* __restrict__ A,
        const unsigned short* __restrict__ B,
        const float* __restrict__ enorm,
        unsigned long long* __restrict__ keys) {
    __shared__ __align__(16) unsigned short Al[3][8192];   // 3 x 16 KB (256r x 32k)
    __shared__ __align__(16) unsigned short Bl[3][4096];   // 3 x  8 KB (128r x 32k)

    const int tid  = threadIdx.x;
    const int lane = tid & 63;
    const int wid  = tid >> 6;
    const int wr   = wid >> 1;      // 0..1 -> 128-row half of A-tile
    const int wc   = wid & 1;       // 0..1 -> 64-col half of B-tile
    const int l31  = lane & 31;
    const int hi5  = lane >> 5;

    // grid 64x64; XCD-bijective + 8x8 super-tile chunking for L2
    const int bid  = blockIdx.x;
    const int swz  = ((bid & 7) << 9) | (bid >> 3);   // 4096 % 8 == 0
    const int stid = swz >> 6, win = swz & 63;
    const int by   = ((stid >> 3) << 3) + (win >> 3);
    const int bx   = ((stid & 7) << 3) + (win & 7);
    const int mBase = by << 8;   // * 256
    const int nBase = bx << 7;   // * 128

    f32x16 acc[4][2];
#pragma unroll
    for (int m = 0; m < 4; m++)
#pragma unroll
        for (int n = 0; n < 2; n++) acc[m][n] = (f32x16)0.f;

    // ---- staging: A 4 calls/thread, B 2 calls/thread, 16B each.
    // slot s -> (row = s>>2, physchunk = s&3); logical chunk = phys ^ ((row>>1)&3)
    // (source pre-swizzle; LDS dest stays linear: rule #21).
    const unsigned short* pA[4];
    int dA[4];
#pragma unroll
    for (int c = 0; c < 4; c++) {
        int slot = (wid * 4 + c) * 64 + lane;        // 0..1023
        int row  = slot >> 2;
        int lg   = (slot & 3) ^ ((row >> 1) & 3);
        pA[c] = A + (size_t)(mBase + row) * KSPLIT + lg * 8;
        dA[c] = slot * 8;                            // shorts
    }
    const unsigned short* pB[2];
    int dB[2];
#pragma unroll
    for (int c = 0; c < 2; c++) {
        int slot = (wid * 2 + c) * 64 + lane;        // 0..511
        int row  = slot >> 2;
        int lg   = (slot & 3) ^ ((row >> 1) & 3);
        pB[c] = B + (size_t)(nBase + row) * KSPLIT + lg * 8;
        dB[c] = slot * 8;
    }

#define STAGE(bufn, t) do { \
    _Pragma("unroll") for (int c = 0; c < 4; c++) \
        GLOAD_LDS16(pA[c] + (t) * 32, &Al[bufn][dA[c]]); \
    _Pragma("unroll") for (int c = 0; c < 2; c++) \
        GLOAD_LDS16(pB[c] + (t) * 32, &Bl[bufn][dB[c]]); \
} while (0)

    // ---- read offsets: row R, logical chunk c(ks,hi5) -> phys = c ^ ((R>>1)&3);
    // (R>>1)&3 == (l31>>1)&3 for all our rows (row = mult32 + l31).
    const int cx = (l31 >> 1) & 3;
    const int co0 = ((0 * 2 + hi5) ^ cx) * 8;   // ks=0, shorts
    const int co1 = ((1 * 2 + hi5) ^ cx) * 8;   // ks=1
    int arow[4], brow[2];
#pragma unroll
    for (int m = 0; m < 4; m++) arow[m] = (wr * 128 + m * 32 + l31) * 32;
#pragma unroll
    for (int n = 0; n < 2; n++) brow[n] = (wc * 64 + n * 32 + l31) * 32;

    STAGE(0, 0);
    STAGE(1, 1);

    int b0 = 0, b1 = 1, b2 = 2;
    for (int t = 0; t < 24; ++t) {
        if (t < 23) asm volatile("s_waitcnt vmcnt(6)" ::: "memory");
        else        asm volatile("s_waitcnt vmcnt(0)" ::: "memory");
        asm volatile("s_barrier" ::: "memory");
        if (t < 22) STAGE(b2, t + 2);

        short8 af[4][2], bf[2][2];
#pragma unroll
        for (int m = 0; m < 4; m++) {
            af[m][0] = *(const short8*)&Al[b0][arow[m] + co0];
            af[m][1] = *(const short8*)&Al[b0][arow[m] + co1];
        }
#pragma unroll
        for (int n = 0; n < 2; n++) {
            bf[n][0] = *(const short8*)&Bl[b0][brow[n] + co0];
            bf[n][1] = *(const short8*)&Bl[b0][brow[n] + co1];
        }
        asm volatile("s_waitcnt lgkmcnt(0)" ::: "memory");
        __builtin_amdgcn_sched_barrier(0);
        __builtin_amdgcn_s_setprio(1);
#pragma unroll
        for (int m = 0; m < 4; m++)
#pragma unroll
            for (int n = 0; n < 2; n++) {
                acc[m][n] = __builtin_amdgcn_mfma_f32_32x32x16_bf16(
                    af[m][0], bf[n][0], acc[m][n], 0, 0, 0);
                acc[m][n] = __builtin_amdgcn_mfma_f32_32x32x16_bf16(
                    af[m][1], bf[n][1], acc[m][n], 0, 0, 0);
            }
        __builtin_amdgcn_s_setprio(0);

        int nb0 = b1; b1 = b2; b2 = b0; b0 = nb0;   // rotate buffers
    }
#undef STAGE

    // ---- epilogue: score = ||e||^2 - 2*dot; argmin per row (32x32 C/D layout:
    // col = lane&31, row = (reg&3) + 8*(reg>>2) + 4*(lane>>5)  [m74/m101])
    float en[2];
    int   cc[2];
#pragma unroll
    for (int n = 0; n < 2; n++) {
        cc[n] = nBase + wc * 64 + n * 32 + l31;
        en[n] = enorm[cc[n]];
    }
#pragma unroll
    for (int m = 0; m < 4; m++) {
#pragma unroll
        for (int r = 0; r < 16; r++) {
            float s0 = en[0] - 2.f * acc[m][0][r];
            float s1 = en[1] - 2.f * acc[m][1][r];
            float bs = s0; int bc = cc[0];
            if (s1 < bs) { bs = s1; bc = cc[1]; }   // tie -> lower col (cc0<cc1)
            unsigned long long key =
                ((unsigned long long)fkey(bs) << 32) | (unsigned int)bc;
#pragma unroll
            for (int msk = 16; msk >= 1; msk >>= 1) {
                unsigned long long o = __shfl_xor(key, msk, 64);
                if (o < key) key = o;
            }
            if (l31 == 0) {
                int grow = mBase + wr * 128 + m * 32 + (r & 3) + 8 * (r >> 2) + 4 * hi5;
                atomicMin(&keys[grow], key);
            }
        }
    }
}

// ---------- fallback fp32 fused GEMM+argmin ----------
#define BM 64
#define BN 256
#define KB 16
#define NSPLIT 4

__global__ __launch_bounds__(256) void argmin_kernel(const float* __restrict__ x,
                                                     const float* __restrict__ embed,
                                                     const float* __restrict__ enorm,
                                                     unsigned long long* __restrict__ keys) {
    __shared__ float xs[KB][BM];
    __shared__ float es[KB][BN];

    const int tid = threadIdx.x;
    const int tx = tid & 31;
    const int ty = tid >> 5;
    const int rowBase = blockIdx.x * BM;
    const int cStart = blockIdx.y * (CBOOK / NSPLIT);

    float bestS[8];
    int   bestC[8];
#pragma unroll
    for (int i = 0; i < 8; i++) { bestS[i] = 3.4e38f; bestC[i] = 0; }

    float acc[8][8];

    for (int cb = 0; cb < CBOOK / NSPLIT; cb += BN) {
        const int cbase = cStart + cb;
#pragma unroll
        for (int i = 0; i < 8; i++)
#pragma unroll
            for (int j = 0; j < 8; j++) acc[i][j] = 0.f;

        for (int kk = 0; kk < DIM; kk += KB) {
            __syncthreads();
            {
                int r  = tid >> 2;
                int k4 = (tid & 3) * 4;
                float4 v = *(const float4*)&x[(rowBase + r) * DIM + kk + k4];
                xs[k4 + 0][r] = v.x; xs[k4 + 1][r] = v.y;
                xs[k4 + 2][r] = v.z; xs[k4 + 3][r] = v.w;
            }
            {
                const float4* src = (const float4*)&embed[(cbase + tid) * DIM + kk];
#pragma unroll
                for (int q = 0; q < 4; q++) {
                    float4 v = src[q];
                    es[q * 4 + 0][tid] = v.x; es[q * 4 + 1][tid] = v.y;
                    es[q * 4 + 2][tid] = v.z; es[q * 4 + 3][tid] = v.w;
                }
            }
            __syncthreads();
#pragma unroll
            for (int k = 0; k < KB; k++) {
                float xr[8], er[8];
                *(float4*)&xr[0] = *(const float4*)&xs[k][ty * 8];
                *(float4*)&xr[4] = *(const float4*)&xs[k][ty * 8 + 4];
                *(float4*)&er[0] = *(const float4*)&es[k][tx * 4];
                *(float4*)&er[4] = *(const float4*)&es[k][128 + tx * 4];
#pragma unroll
                for (int i = 0; i < 8; i++)
#pragma unroll
                    for (int j = 0; j < 8; j++)
                        acc[i][j] = fmaf(xr[i], er[j], acc[i][j]);
            }
        }
#pragma unroll
        for (int j = 0; j < 8; j++) {
            int c = cbase + ((j < 4) ? (tx * 4 + j) : (128 + tx * 4 + (j - 4)));
            float en = enorm[c];
#pragma unroll
            for (int i = 0; i < 8; i++) {
                float s = en - 2.f * acc[i][j];
                if (s < bestS[i]) { bestS[i] = s; bestC[i] = c; }
            }
        }
    }

#pragma unroll
    for (int i = 0; i < 8; i++) {
        unsigned long long key =
            ((unsigned long long)fkey(bestS[i]) << 32) | (unsigned int)bestC[i];
        for (int m = 16; m >= 1; m >>= 1) {
            unsigned long long o = __shfl_xor(key, m, 64);
            if (o < key) key = o;
        }
        if (tx == 0) atomicMin(&keys[rowBase + ty * 8 + i], key);
    }
}

// ---------- scatter: quantize gather, ind write, counts, 0.2*x into avg ----------
__global__ __launch_bounds__(256) void scatter_kernel(const float* __restrict__ x,
                                                      const float* __restrict__ embed,
                                                      const unsigned long long* __restrict__ keys,
                                                      float* __restrict__ quant,
                                                      float* __restrict__ ind_out,
                                                      float* __restrict__ counts,
                                                      float* __restrict__ avg_out) {
    int i = blockIdx.x * 256 + threadIdx.x;
    int row = i >> 6;
    int c4  = (i & 63) * 4;
    int idx = (int)(keys[row] & 0xFFFFFFFFull);
    float4 e = *(const float4*)&embed[idx * DIM + c4];
    *(float4*)&quant[row * DIM + c4] = e;
    float4 xv = *(const float4*)&x[row * DIM + c4];
    atomicAdd(&avg_out[idx * DIM + c4 + 0], OMD_F * xv.x);
    atomicAdd(&avg_out[idx * DIM + c4 + 1], OMD_F * xv.y);
    atomicAdd(&avg_out[idx * DIM + c4 + 2], OMD_F * xv.z);
    atomicAdd(&avg_out[idx * DIM + c4 + 3], OMD_F * xv.w);
    if ((i & 63) == 0) {
        ind_out[row] = (float)idx;
        atomicAdd(&counts[idx], 1.0f);
    }
}

// ---------- cluster_size_new + total sum ----------
__global__ __launch_bounds__(256) void csn_kernel(const float* __restrict__ cluster_size,
                                                  const float* __restrict__ counts,
                                                  float* __restrict__ csn_out,
                                                  float* __restrict__ total) {
    int c = blockIdx.x * 256 + threadIdx.x;
    float v = DECAY_F * cluster_size[c] + OMD_F * counts[c];
    csn_out[c] = v;
    float s = v;
    for (int m = 32; m >= 1; m >>= 1) s += __shfl_xor(s, m, 64);
    __shared__ float ws4[4];
    if ((threadIdx.x & 63) == 0) ws4[threadIdx.x >> 6] = s;
    __syncthreads();
    if (threadIdx.x == 0) atomicAdd(total, ws4[0] + ws4[1] + ws4[2] + ws4[3]);
}

// ---------- embed_normalized = avg_new / cs ----------
__global__ __launch_bounds__(256) void norm_kernel(const float* __restrict__ avg_new,
                                                   const float* __restrict__ csn,
                                                   const float* __restrict__ total,
                                                   float* __restrict__ out) {
    int i = blockIdx.x * 256 + threadIdx.x;
    int c = i >> 6;
    float tot = *total;
    float smoothed = (csn[c] + EPS_F) / (tot + (float)CBOOK * EPS_F);
    float cs = smoothed * tot;
    float4 v = ((const float4*)avg_new)[i];
    v.x = v.x / cs; v.y = v.y / cs; v.z = v.z / cs; v.w = v.w / cs;
    ((float4*)out)[i] = v;
}

extern "C" void kernel_launch(void* const* d_in, const int* in_sizes, int n_in,
                              void* d_out, int out_size, void* d_ws, size_t ws_size,
                              hipStream_t stream) {
    const float* x            = (const float*)d_in[0];
    const float* embed        = (const float*)d_in[1];
    const float* cluster_size = (const float*)d_in[2];
    const float* embed_avg    = (const float*)d_in[3];
    float* out = (float*)d_out;
    char*  ws  = (char*)d_ws;

    unsigned long long* keys = (unsigned long long*)(ws + WS_KEYS);
    float* enorm  = (float*)(ws + WS_ENORM);
    float* counts = (float*)(ws + WS_COUNTS);
    float* total  = (float*)(ws + WS_TOTAL);

    hipMemsetAsync(ws + WS_KEYS, 0xFF, NROWS * 8, stream);
    hipMemsetAsync(ws + WS_COUNTS, 0, CBOOK * 4 + 4, stream);

    init_avg_kernel<<<(CBOOK * DIM / 4) / 256, 256, 0, stream>>>(embed_avg, out + O_AVG);

    if (ws_size >= (size_t)WS_NEED) {
        unsigned short* xsplit = (unsigned short*)(ws + WS_XSPLIT);
        unsigned short* esplit = (unsigned short*)(ws + WS_ESPLIT_OFF);
        xsplit_kernel<<<(NROWS * DIM / 4) / 256, 256, 0, stream>>>(x, xsplit);
        esplit_kernel<<<CBOOK / 4, 256, 0, stream>>>(embed, esplit, enorm);
        mfma32_argmin_kernel<<<(NROWS / 256) * (CBOOK / 128), 256, 0, stream>>>(
            xsplit, esplit, enorm, keys);
    } else {
        esplit_kernel<<<CBOOK / 4, 256, 0, stream>>>(embed, (unsigned short*)(ws + WS_XSPLIT), enorm);
        dim3 grid(NROWS / BM, NSPLIT);
        argmin_kernel<<<grid, 256, 0, stream>>>(x, embed, enorm, keys);
    }

    scatter_kernel<<<(NROWS * DIM / 4) / 256, 256, 0, stream>>>(
        x, embed, keys, out + O_QUANT, out + O_IND, counts, out + O_AVG);

    csn_kernel<<<CBOOK / 256, 256, 0, stream>>>(cluster_size, counts, out + O_CSN, total);

    norm_kernel<<<(CBOOK * DIM / 4) / 256, 256, 0, stream>>>(
        out + O_AVG, out + O_CSN, total, out + O_NORM);
}

// Round 7
// 471.744 us; speedup vs baseline: 1.3235x; 1.0045x over previous
//
#include <hip/hip_runtime.h>
#include <hip/hip_bf16.h>

#define DECAY_F 0.8f
#define OMD_F   0.2f
#define EPS_F   1e-5f

#define NROWS 16384
#define CBOOK 8192
#define DIM   256
#define KSPLIT 768   // [hi | lo | hi] x [hi | hi | lo]

// ---- ws layout (bytes) ----
#define WS_KEYS   0u
#define WS_ENORM  131072u
#define WS_COUNTS 163840u
#define WS_TOTAL  196608u
#define WS_XSPLIT 262144u
#define WS_ESPLIT_OFF (262144u + 25165824u)
#define WS_NEED   (WS_ESPLIT_OFF + 12582912u)

// ---- d_out layout (floats) ----
#define O_QUANT 0
#define O_IND   4194304
#define O_NORM  4210688
#define O_CSN   6307840
#define O_AVG   6316032

typedef __attribute__((ext_vector_type(8)))  short short8;
typedef __attribute__((ext_vector_type(4)))  float f32x4;
typedef __attribute__((ext_vector_type(16))) float f32x16;
typedef __attribute__((ext_vector_type(4)))  unsigned short us4;

__device__ __forceinline__ unsigned int fkey(float f) {
    unsigned int b = __float_as_uint(f);
    return (b & 0x80000000u) ? ~b : (b | 0x80000000u);
}
__device__ __forceinline__ unsigned short f2bf(float f) {
    unsigned int u = __float_as_uint(f);
    unsigned int r = (u + 0x7FFFu + ((u >> 16) & 1u)) >> 16;
    return (unsigned short)r;
}
__device__ __forceinline__ float bf2f(unsigned short h) {
    return __uint_as_float(((unsigned int)h) << 16);
}

#define GLOAD_LDS16(g, l) \
    __builtin_amdgcn_global_load_lds((const __attribute__((address_space(1))) void*)(g), \
                                     (__attribute__((address_space(3))) void*)(l), 16, 0, 0)

// ---------- init embed_avg_new = 0.8*embed_avg ----------
__global__ __launch_bounds__(256) void init_avg_kernel(const float* __restrict__ embed_avg,
                                                       float* __restrict__ avg_out) {
    int i = blockIdx.x * 256 + threadIdx.x;
    float4 v = ((const float4*)embed_avg)[i];
    v.x *= DECAY_F; v.y *= DECAY_F; v.z *= DECAY_F; v.w *= DECAY_F;
    ((float4*)avg_out)[i] = v;
}

// ---------- x split: [hi, lo, hi] ----------
__global__ __launch_bounds__(256) void xsplit_kernel(const float* __restrict__ src,
                                                     unsigned short* __restrict__ dst) {
    int i = blockIdx.x * 256 + threadIdx.x;
    int e4  = i * 4;
    int row = e4 >> 8;
    int k   = e4 & 255;
    float4 v = ((const float4*)src)[i];
    us4 hi, lo;
    hi.x = f2bf(v.x); lo.x = f2bf(v.x - bf2f(hi.x));
    hi.y = f2bf(v.y); lo.y = f2bf(v.y - bf2f(hi.y));
    hi.z = f2bf(v.z); lo.z = f2bf(v.z - bf2f(hi.z));
    hi.w = f2bf(v.w); lo.w = f2bf(v.w - bf2f(hi.w));
    unsigned short* base = dst + (size_t)row * KSPLIT + k;
    *(us4*)(base + 0)   = hi;
    *(us4*)(base + 256) = lo;
    *(us4*)(base + 512) = hi;
}

// ---------- e split [hi, hi, lo] + fused ||e||^2 ----------
__global__ __launch_bounds__(256) void esplit_kernel(const float* __restrict__ embed,
                                                     unsigned short* __restrict__ dst,
                                                     float* __restrict__ enorm) {
    int row  = (blockIdx.x * 256 + threadIdx.x) >> 6;
    int lane = threadIdx.x & 63;
    float4 v = *(const float4*)&embed[row * DIM + lane * 4];
    float s = v.x * v.x + v.y * v.y + v.z * v.z + v.w * v.w;
    for (int m = 32; m >= 1; m >>= 1) s += __shfl_xor(s, m, 64);
    if (lane == 0) enorm[row] = s;
    us4 hi, lo;
    hi.x = f2bf(v.x); lo.x = f2bf(v.x - bf2f(hi.x));
    hi.y = f2bf(v.y); lo.y = f2bf(v.y - bf2f(hi.y));
    hi.z = f2bf(v.z); lo.z = f2bf(v.z - bf2f(hi.z));
    hi.w = f2bf(v.w); lo.w = f2bf(v.w - bf2f(hi.w));
    unsigned short* base = dst + (size_t)row * KSPLIT + lane * 4;
    *(us4*)(base + 0)   = hi;
    *(us4*)(base + 256) = hi;
    *(us4*)(base + 512) = lo;
}

// ============ 32x32x16 MFMA GEMM (K=768) + fused per-row argmin ============
// Block 256x128, 4 waves (2x2), wave = 128x64 (M_rep4 x N_rep2 of 32x32 frags).
// BK=32, 3 LDS buffers, depth-2 prefetch, counted vmcnt(6), ONE s_barrier/tile.
// R7 fix: MFMA issue order ks-outer -> 8 INDEPENDENT MFMAs per group (R6 issued
// dependent acc pairs back-to-back, paying MFMA latency every 2nd op).
// Split lgkm wait: ks0 MFMAs run while ks1 ds_reads complete.
__global__ __launch_bounds__(256, 2) void mfma32_argmin_kernel(
        const unsigned short* __restrict__ A,
        const unsigned short* __restrict__ B,
        const float* __restrict__ enorm,
        unsigned long long* __restrict__ keys) {
    __shared__ __align__(16) unsigned short Al[3][8192];   // 3 x 16 KB (256r x 32k)
    __shared__ __align__(16) unsigned short Bl[3][4096];   // 3 x  8 KB (128r x 32k)

    const int tid  = threadIdx.x;
    const int lane = tid & 63;
    const int wid  = tid >> 6;
    const int wr   = wid >> 1;      // 0..1 -> 128-row half of A-tile
    const int wc   = wid & 1;       // 0..1 -> 64-col half of B-tile
    const int l31  = lane & 31;
    const int hi5  = lane >> 5;

    // grid 64x64; XCD-bijective + 8x8 super-tile chunking for L2
    const int bid  = blockIdx.x;
    const int swz  = ((bid & 7) << 9) | (bid >> 3);   // 4096 % 8 == 0
    const int stid = swz >> 6, win = swz & 63;
    const int by   = ((stid >> 3) << 3) + (win >> 3);
    const int bx   = ((stid & 7) << 3) + (win & 7);
    const int mBase = by << 8;   // * 256
    const int nBase = bx << 7;   // * 128

    f32x16 acc[4][2];
#pragma unroll
    for (int m = 0; m < 4; m++)
#pragma unroll
        for (int n = 0; n < 2; n++) acc[m][n] = (f32x16)0.f;

    // ---- staging: A 4 calls/thread, B 2 calls/thread, 16B each.
    // slot s -> (row = s>>2, physchunk = s&3); logical chunk = phys ^ ((row>>1)&3)
    // (source pre-swizzle; LDS dest stays linear: rule #21).
    const unsigned short* pA[4];
    int dA[4];
#pragma unroll
    for (int c = 0; c < 4; c++) {
        int slot = (wid * 4 + c) * 64 + lane;        // 0..1023
        int row  = slot >> 2;
        int lg   = (slot & 3) ^ ((row >> 1) & 3);
        pA[c] = A + (size_t)(mBase + row) * KSPLIT + lg * 8;
        dA[c] = slot * 8;                            // shorts
    }
    const unsigned short* pB[2];
    int dB[2];
#pragma unroll
    for (int c = 0; c < 2; c++) {
        int slot = (wid * 2 + c) * 64 + lane;        // 0..511
        int row  = slot >> 2;
        int lg   = (slot & 3) ^ ((row >> 1) & 3);
        pB[c] = B + (size_t)(nBase + row) * KSPLIT + lg * 8;
        dB[c] = slot * 8;
    }

#define STAGE(bufn, t) do { \
    _Pragma("unroll") for (int c = 0; c < 4; c++) \
        GLOAD_LDS16(pA[c] + (t) * 32, &Al[bufn][dA[c]]); \
    _Pragma("unroll") for (int c = 0; c < 2; c++) \
        GLOAD_LDS16(pB[c] + (t) * 32, &Bl[bufn][dB[c]]); \
} while (0)

    // ---- read offsets: row R, logical chunk c(ks,hi5) -> phys = c ^ ((R>>1)&3);
    // (R>>1)&3 == (l31>>1)&3 for all our rows (row = mult32 + l31).
    const int cx = (l31 >> 1) & 3;
    const int co0 = ((0 * 2 + hi5) ^ cx) * 8;   // ks=0, shorts
    const int co1 = ((1 * 2 + hi5) ^ cx) * 8;   // ks=1
    int arow[4], brow[2];
#pragma unroll
    for (int m = 0; m < 4; m++) arow[m] = (wr * 128 + m * 32 + l31) * 32;
#pragma unroll
    for (int n = 0; n < 2; n++) brow[n] = (wc * 64 + n * 32 + l31) * 32;

    STAGE(0, 0);
    STAGE(1, 1);

    int b0 = 0, b1 = 1, b2 = 2;
    for (int t = 0; t < 24; ++t) {
        if (t < 23) asm volatile("s_waitcnt vmcnt(6)" ::: "memory");
        else        asm volatile("s_waitcnt vmcnt(0)" ::: "memory");
        asm volatile("s_barrier" ::: "memory");
        if (t < 22) STAGE(b2, t + 2);

        short8 af[4][2], bf[2][2];
        // issue ks0 reads first (6), then ks1 (6); order pinned so lgkmcnt(6)
        // means "ks0 group complete".
#pragma unroll
        for (int m = 0; m < 4; m++) af[m][0] = *(const short8*)&Al[b0][arow[m] + co0];
#pragma unroll
        for (int n = 0; n < 2; n++) bf[n][0] = *(const short8*)&Bl[b0][brow[n] + co0];
        __builtin_amdgcn_sched_barrier(0);
#pragma unroll
        for (int m = 0; m < 4; m++) af[m][1] = *(const short8*)&Al[b0][arow[m] + co1];
#pragma unroll
        for (int n = 0; n < 2; n++) bf[n][1] = *(const short8*)&Bl[b0][brow[n] + co1];

        asm volatile("s_waitcnt lgkmcnt(6)" ::: "memory");
        __builtin_amdgcn_sched_barrier(0);
        __builtin_amdgcn_s_setprio(1);
#pragma unroll
        for (int m = 0; m < 4; m++)
#pragma unroll
            for (int n = 0; n < 2; n++)
                acc[m][n] = __builtin_amdgcn_mfma_f32_32x32x16_bf16(
                    af[m][0], bf[n][0], acc[m][n], 0, 0, 0);
        __builtin_amdgcn_s_setprio(0);

        asm volatile("s_waitcnt lgkmcnt(0)" ::: "memory");
        __builtin_amdgcn_sched_barrier(0);
        __builtin_amdgcn_s_setprio(1);
#pragma unroll
        for (int m = 0; m < 4; m++)
#pragma unroll
            for (int n = 0; n < 2; n++)
                acc[m][n] = __builtin_amdgcn_mfma_f32_32x32x16_bf16(
                    af[m][1], bf[n][1], acc[m][n], 0, 0, 0);
        __builtin_amdgcn_s_setprio(0);

        int nb0 = b1; b1 = b2; b2 = b0; b0 = nb0;   // rotate buffers
    }
#undef STAGE

    // ---- epilogue: score = ||e||^2 - 2*dot; argmin per row (32x32 C/D layout:
    // col = lane&31, row = (reg&3) + 8*(reg>>2) + 4*(lane>>5)  [m74/m101])
    float en[2];
    int   cc[2];
#pragma unroll
    for (int n = 0; n < 2; n++) {
        cc[n] = nBase + wc * 64 + n * 32 + l31;
        en[n] = enorm[cc[n]];
    }
#pragma unroll
    for (int m = 0; m < 4; m++) {
#pragma unroll
        for (int r = 0; r < 16; r++) {
            float s0 = en[0] - 2.f * acc[m][0][r];
            float s1 = en[1] - 2.f * acc[m][1][r];
            float bs = s0; int bc = cc[0];
            if (s1 < bs) { bs = s1; bc = cc[1]; }   // tie -> lower col (cc0<cc1)
            unsigned long long key =
                ((unsigned long long)fkey(bs) << 32) | (unsigned int)bc;
#pragma unroll
            for (int msk = 16; msk >= 1; msk >>= 1) {
                unsigned long long o = __shfl_xor(key, msk, 64);
                if (o < key) key = o;
            }
            if (l31 == 0) {
                int grow = mBase + wr * 128 + m * 32 + (r & 3) + 8 * (r >> 2) + 4 * hi5;
                atomicMin(&keys[grow], key);
            }
        }
    }
}

// ---------- fallback fp32 fused GEMM+argmin ----------
#define BM 64
#define BN 256
#define KB 16
#define NSPLIT 4

__global__ __launch_bounds__(256) void argmin_kernel(const float* __restrict__ x,
                                                     const float* __restrict__ embed,
                                                     const float* __restrict__ enorm,
                                                     unsigned long long* __restrict__ keys) {
    __shared__ float xs[KB][BM];
    __shared__ float es[KB][BN];

    const int tid = threadIdx.x;
    const int tx = tid & 31;
    const int ty = tid >> 5;
    const int rowBase = blockIdx.x * BM;
    const int cStart = blockIdx.y * (CBOOK / NSPLIT);

    float bestS[8];
    int   bestC[8];
#pragma unroll
    for (int i = 0; i < 8; i++) { bestS[i] = 3.4e38f; bestC[i] = 0; }

    float acc[8][8];

    for (int cb = 0; cb < CBOOK / NSPLIT; cb += BN) {
        const int cbase = cStart + cb;
#pragma unroll
        for (int i = 0; i < 8; i++)
#pragma unroll
            for (int j = 0; j < 8; j++) acc[i][j] = 0.f;

        for (int kk = 0; kk < DIM; kk += KB) {
            __syncthreads();
            {
                int r  = tid >> 2;
                int k4 = (tid & 3) * 4;
                float4 v = *(const float4*)&x[(rowBase + r) * DIM + kk + k4];
                xs[k4 + 0][r] = v.x; xs[k4 + 1][r] = v.y;
                xs[k4 + 2][r] = v.z; xs[k4 + 3][r] = v.w;
            }
            {
                const float4* src = (const float4*)&embed[(cbase + tid) * DIM + kk];
#pragma unroll
                for (int q = 0; q < 4; q++) {
                    float4 v = src[q];
                    es[q * 4 + 0][tid] = v.x; es[q * 4 + 1][tid] = v.y;
                    es[q * 4 + 2][tid] = v.z; es[q * 4 + 3][tid] = v.w;
                }
            }
            __syncthreads();
#pragma unroll
            for (int k = 0; k < KB; k++) {
                float xr[8], er[8];
                *(float4*)&xr[0] = *(const float4*)&xs[k][ty * 8];
                *(float4*)&xr[4] = *(const float4*)&xs[k][ty * 8 + 4];
                *(float4*)&er[0] = *(const float4*)&es[k][tx * 4];
                *(float4*)&er[4] = *(const float4*)&es[k][128 + tx * 4];
#pragma unroll
                for (int i = 0; i < 8; i++)
#pragma unroll
                    for (int j = 0; j < 8; j++)
                        acc[i][j] = fmaf(xr[i], er[j], acc[i][j]);
            }
        }
#pragma unroll
        for (int j = 0; j < 8; j++) {
            int c = cbase + ((j < 4) ? (tx * 4 + j) : (128 + tx * 4 + (j - 4)));
            float en = enorm[c];
#pragma unroll
            for (int i = 0; i < 8; i++) {
                float s = en - 2.f * acc[i][j];
                if (s < bestS[i]) { bestS[i] = s; bestC[i] = c; }
            }
        }
    }

#pragma unroll
    for (int i = 0; i < 8; i++) {
        unsigned long long key =
            ((unsigned long long)fkey(bestS[i]) << 32) | (unsigned int)bestC[i];
        for (int m = 16; m >= 1; m >>= 1) {
            unsigned long long o = __shfl_xor(key, m, 64);
            if (o < key) key = o;
        }
        if (tx == 0) atomicMin(&keys[rowBase + ty * 8 + i], key);
    }
}

// ---------- scatter: quantize gather, ind write, counts, 0.2*x into avg ----------
__global__ __launch_bounds__(256) void scatter_kernel(const float* __restrict__ x,
                                                      const float* __restrict__ embed,
                                                      const unsigned long long* __restrict__ keys,
                                                      float* __restrict__ quant,
                                                      float* __restrict__ ind_out,
                                                      float* __restrict__ counts,
                                                      float* __restrict__ avg_out) {
    int i = blockIdx.x * 256 + threadIdx.x;
    int row = i >> 6;
    int c4  = (i & 63) * 4;
    int idx = (int)(keys[row] & 0xFFFFFFFFull);
    float4 e = *(const float4*)&embed[idx * DIM + c4];
    *(float4*)&quant[row * DIM + c4] = e;
    float4 xv = *(const float4*)&x[row * DIM + c4];
    atomicAdd(&avg_out[idx * DIM + c4 + 0], OMD_F * xv.x);
    atomicAdd(&avg_out[idx * DIM + c4 + 1], OMD_F * xv.y);
    atomicAdd(&avg_out[idx * DIM + c4 + 2], OMD_F * xv.z);
    atomicAdd(&avg_out[idx * DIM + c4 + 3], OMD_F * xv.w);
    if ((i & 63) == 0) {
        ind_out[row] = (float)idx;
        atomicAdd(&counts[idx], 1.0f);
    }
}

// ---------- cluster_size_new + total sum ----------
__global__ __launch_bounds__(256) void csn_kernel(const float* __restrict__ cluster_size,
                                                  const float* __restrict__ counts,
                                                  float* __restrict__ csn_out,
                                                  float* __restrict__ total) {
    int c = blockIdx.x * 256 + threadIdx.x;
    float v = DECAY_F * cluster_size[c] + OMD_F * counts[c];
    csn_out[c] = v;
    float s = v;
    for (int m = 32; m >= 1; m >>= 1) s += __shfl_xor(s, m, 64);
    __shared__ float ws4[4];
    if ((threadIdx.x & 63) == 0) ws4[threadIdx.x >> 6] = s;
    __syncthreads();
    if (threadIdx.x == 0) atomicAdd(total, ws4[0] + ws4[1] + ws4[2] + ws4[3]);
}

// ---------- embed_normalized = avg_new / cs ----------
__global__ __launch_bounds__(256) void norm_kernel(const float* __restrict__ avg_new,
                                                   const float* __restrict__ csn,
                                                   const float* __restrict__ total,
                                                   float* __restrict__ out) {
    int i = blockIdx.x * 256 + threadIdx.x;
    int c = i >> 6;
    float tot = *total;
    float smoothed = (csn[c] + EPS_F) / (tot + (float)CBOOK * EPS_F);
    float cs = smoothed * tot;
    float4 v = ((const float4*)avg_new)[i];
    v.x = v.x / cs; v.y = v.y / cs; v.z = v.z / cs; v.w = v.w / cs;
    ((float4*)out)[i] = v;
}

extern "C" void kernel_launch(void* const* d_in, const int* in_sizes, int n_in,
                              void* d_out, int out_size, void* d_ws, size_t ws_size,
                              hipStream_t stream) {
    const float* x            = (const float*)d_in[0];
    const float* embed        = (const float*)d_in[1];
    const float* cluster_size = (const float*)d_in[2];
    const float* embed_avg    = (const float*)d_in[3];
    float* out = (float*)d_out;
    char*  ws  = (char*)d_ws;

    unsigned long long* keys = (unsigned long long*)(ws + WS_KEYS);
    float* enorm  = (float*)(ws + WS_ENORM);
    float* counts = (float*)(ws + WS_COUNTS);
    float* total  = (float*)(ws + WS_TOTAL);

    hipMemsetAsync(ws + WS_KEYS, 0xFF, NROWS * 8, stream);
    hipMemsetAsync(ws + WS_COUNTS, 0, CBOOK * 4 + 4, stream);

    init_avg_kernel<<<(CBOOK * DIM / 4) / 256, 256, 0, stream>>>(embed_avg, out + O_AVG);

    if (ws_size >= (size_t)WS_NEED) {
        unsigned short* xsplit = (unsigned short*)(ws + WS_XSPLIT);
        unsigned short* esplit = (unsigned short*)(ws + WS_ESPLIT_OFF);
        xsplit_kernel<<<(NROWS * DIM / 4) / 256, 256, 0, stream>>>(x, xsplit);
        esplit_kernel<<<CBOOK / 4, 256, 0, stream>>>(embed, esplit, enorm);
        mfma32_argmin_kernel<<<(NROWS / 256) * (CBOOK / 128), 256, 0, stream>>>(
            xsplit, esplit, enorm, keys);
    } else {
        esplit_kernel<<<CBOOK / 4, 256, 0, stream>>>(embed, (unsigned short*)(ws + WS_XSPLIT), enorm);
        dim3 grid(NROWS / BM, NSPLIT);
        argmin_kernel<<<grid, 256, 0, stream>>>(x, embed, enorm, keys);
    }

    scatter_kernel<<<(NROWS * DIM / 4) / 256, 256, 0, stream>>>(
        x, embed, keys, out + O_QUANT, out + O_IND, counts, out + O_AVG);

    csn_kernel<<<CBOOK / 256, 256, 0, stream>>>(cluster_size, counts, out + O_CSN, total);

    norm_kernel<<<(CBOOK * DIM / 4) / 256, 256, 0, stream>>>(
        out + O_AVG, out + O_CSN, total, out + O_NORM);
}